// Round 3
// baseline (515.144 us; speedup 1.0000x reference)
//
#include <hip/hip_runtime.h>
#include <hip/hip_bf16.h>
#include <cstdint>
#include <type_traits>

using bf16_t = __hip_bfloat16;
typedef __bf16 bf16x8 __attribute__((ext_vector_type(8)));
typedef float f32x4 __attribute__((ext_vector_type(4)));

typedef __attribute__((address_space(3))) uint32_t lds_u32_t;
typedef const __attribute__((address_space(1))) uint32_t glb_u32_t;

// ---------------- f32 -> bf16 convert, 8 elems/thread ----------------
__global__ void cvt_f32_to_bf16(const float* __restrict__ in, bf16_t* __restrict__ out, int n8) {
  int stride = gridDim.x * blockDim.x;
  for (int i = blockIdx.x * blockDim.x + threadIdx.x; i < n8; i += stride) {
    const float4* p = reinterpret_cast<const float4*>(in) + (size_t)i * 2;
    float4 a = p[0];
    float4 b = p[1];
    bf16_t o[8];
    o[0] = __float2bfloat16(a.x); o[1] = __float2bfloat16(a.y);
    o[2] = __float2bfloat16(a.z); o[3] = __float2bfloat16(a.w);
    o[4] = __float2bfloat16(b.x); o[5] = __float2bfloat16(b.y);
    o[6] = __float2bfloat16(b.z); o[7] = __float2bfloat16(b.w);
    *reinterpret_cast<uint4*>(out + (size_t)i * 8) = *reinterpret_cast<const uint4*>(o);
  }
}

// ---------------- bf16 GEMM: C[M,N] = A[M,K] * Bt[N,K]^T ----------------
// 128x128 tile, BK=32, 4 waves (2x2 of 64x64), mfma_f32_16x16x32_bf16.
// Staging via global_load_lds width=16 (m97 pattern), 2-barrier K-loop.
template <typename OutT>
__global__ __launch_bounds__(256) void gemm_bt(const bf16_t* __restrict__ A,
                                               const bf16_t* __restrict__ Bt,
                                               OutT* __restrict__ C,
                                               int M, int N, int K) {
  __shared__ __align__(16) bf16_t As[128 * 32];
  __shared__ __align__(16) bf16_t Bs[128 * 32];
  const int tid = threadIdx.x;
  const int lane = tid & 63;
  const int w = tid >> 6;
  const int wm = w >> 1, wn = w & 1;
  const int lr = lane & 15, lc = lane >> 4;
  const int m0 = blockIdx.y * 128, n0 = blockIdx.x * 128;

  // staging chunks: chunk c covers row c>>2, cols (c&3)*8 .. +8 (16B)
  const int c0 = tid, c1 = tid + 256;
  const bf16_t* a0p = A + (size_t)(m0 + (c0 >> 2)) * K + (c0 & 3) * 8;
  const bf16_t* a1p = A + (size_t)(m0 + (c1 >> 2)) * K + (c1 & 3) * 8;
  const bf16_t* b0p = Bt + (size_t)(n0 + (c0 >> 2)) * K + (c0 & 3) * 8;
  const bf16_t* b1p = Bt + (size_t)(n0 + (c1 >> 2)) * K + (c1 & 3) * 8;

  // wave-uniform LDS bases: chunk c lands at byte c*16 = instr*4096 + w*1024 + lane*16
  bf16_t* asb0 = As + w * 512;
  bf16_t* asb1 = As + 2048 + w * 512;
  bf16_t* bsb0 = Bs + w * 512;
  bf16_t* bsb1 = Bs + 2048 + w * 512;

  f32x4 acc[4][4] = {};

  for (int k0 = 0; k0 < K; k0 += 32) {
    __syncthreads();  // previous iter's LDS reads complete
    __builtin_amdgcn_global_load_lds((glb_u32_t*)(a0p + k0), (lds_u32_t*)asb0, 16, 0, 0);
    __builtin_amdgcn_global_load_lds((glb_u32_t*)(a1p + k0), (lds_u32_t*)asb1, 16, 0, 0);
    __builtin_amdgcn_global_load_lds((glb_u32_t*)(b0p + k0), (lds_u32_t*)bsb0, 16, 0, 0);
    __builtin_amdgcn_global_load_lds((glb_u32_t*)(b1p + k0), (lds_u32_t*)bsb1, 16, 0, 0);
    __syncthreads();  // compiler drains vmcnt(0) before barrier -> tiles ready

    bf16x8 af[4], bfv[4];
#pragma unroll
    for (int i = 0; i < 4; ++i)
      af[i] = *reinterpret_cast<const bf16x8*>(&As[(wm * 64 + i * 16 + lr) * 32 + lc * 8]);
#pragma unroll
    for (int i = 0; i < 4; ++i)
      bfv[i] = *reinterpret_cast<const bf16x8*>(&Bs[(wn * 64 + i * 16 + lr) * 32 + lc * 8]);
#pragma unroll
    for (int i = 0; i < 4; ++i)
#pragma unroll
      for (int j = 0; j < 4; ++j)
        acc[i][j] = __builtin_amdgcn_mfma_f32_16x16x32_bf16(af[i], bfv[j], acc[i][j], 0, 0, 0);
  }

  // epilogue: C/D layout col=lane&15, row=(lane>>4)*4+reg  [measured m89/m91]
#pragma unroll
  for (int i = 0; i < 4; ++i)
#pragma unroll
    for (int j = 0; j < 4; ++j) {
      int row = m0 + wm * 64 + i * 16 + lc * 4;
      int col = n0 + wn * 64 + j * 16 + lr;
#pragma unroll
      for (int r = 0; r < 4; ++r) {
        float v = acc[i][j][r];
        if constexpr (std::is_same<OutT, float>::value)
          C[(size_t)(row + r) * N + col] = v;
        else
          C[(size_t)(row + r) * N + col] = __float2bfloat16(v);
      }
    }
}

// ---------------- RoPE + scatter qkv -> Q (scaled), K, V ----------------
// qkv: [B*T][3072] where col = g*768 + slot*128 + d ; slots 0..3 q, 4 k, 5 v
__global__ __launch_bounds__(256) void rope_scatter(const bf16_t* __restrict__ qkv,
                                                    const float* __restrict__ cosp,
                                                    const float* __restrict__ sinp,
                                                    bf16_t* __restrict__ Q,
                                                    bf16_t* __restrict__ K,
                                                    bf16_t* __restrict__ V) {
  const int row = blockIdx.x;  // b*2048 + t
  const int b = row >> 11, t = row & 2047;
  const bf16_t* src = qkv + (size_t)row * 3072;
  for (int n = threadIdx.x; n < 3072; n += 256) {
    int g = n / 768;
    int r = n - g * 768;
    int slot = r >> 7;
    int d = r & 127;
    if (slot == 5) {
      V[(((size_t)(b * 4 + g)) * 2048 + t) * 128 + d] = src[n];
    } else {
      float v = __bfloat162float(src[n]);
      float other = __bfloat162float(src[n ^ 64]);  // bit 6 of n == bit 6 of d
      float c = cosp[t * 128 + d];
      float s = sinp[t * 128 + d];
      float rot = (d < 64) ? -other : other;
      float res = v * c + rot * s;
      if (slot < 4) {
        int h = g * 4 + slot;
        // fold softmax scale 1/sqrt(128) into Q
        Q[(((size_t)(b * 16 + h)) * 2048 + t) * 128 + d] =
            __float2bfloat16(res * 0.08838834764831843f);
      } else {
        K[(((size_t)(b * 4 + g)) * 2048 + t) * 128 + d] = __float2bfloat16(res);
      }
    }
  }
}

// ---------------- V [bg][t][d] -> Vt [bg][d][t] ----------------
__global__ void transpose_v(const bf16_t* __restrict__ V, bf16_t* __restrict__ Vt) {
  __shared__ bf16_t tile[32][33];
  const int bg = blockIdx.z;
  const int t0 = blockIdx.x * 32;
  const int d0 = blockIdx.y * 32;
  const bf16_t* src = V + (size_t)bg * 2048 * 128;
  bf16_t* dst = Vt + (size_t)bg * 128 * 2048;
#pragma unroll
  for (int i = threadIdx.y; i < 32; i += 8)
    tile[i][threadIdx.x] = src[(size_t)(t0 + i) * 128 + d0 + threadIdx.x];
  __syncthreads();
#pragma unroll
  for (int i = threadIdx.y; i < 32; i += 8)
    dst[(size_t)(d0 + i) * 2048 + t0 + threadIdx.x] = tile[threadIdx.x][i];
}

// ---------------- sliding-window flash attention (swapped QK^T) ----------------
// 1 wave per 16-row Q tile; K-tiles of 32; Q pre-scaled; Vt is V^T per (b,g).
// S^T = mfma(K, Q): lane holds S[j-slice][q=lane&15] -> in-register softmax
// (2 shfl_xor per reduce), P stays in registers, O^T = mfma(V^T, P^T) with a
// consistent slot->j permutation on both operands. No LDS at all.
__global__ __launch_bounds__(256) void attn_swa(const bf16_t* __restrict__ Q,
                                                const bf16_t* __restrict__ K,
                                                const bf16_t* __restrict__ Vt,
                                                bf16_t* __restrict__ Y) {
  const int tid = threadIdx.x;
  const int lane = tid & 63;
  const int w = tid >> 6;
  const int lr = lane & 15, lc = lane >> 4;
  const int b = blockIdx.z, h = blockIdx.y;
  const int i0 = (blockIdx.x * 4 + w) * 16;
  const int g = h >> 2;

  const bf16_t* Qp = Q + ((size_t)(b * 16 + h) * 2048) * 128;
  const bf16_t* Kp = K + ((size_t)(b * 4 + g) * 2048) * 128;
  const bf16_t* Vp = Vt + ((size_t)(b * 4 + g) * 128) * 2048;

  const int qrow = i0 + lr;  // this lane's q row (B-operand col)

  bf16x8 qf[4];
#pragma unroll
  for (int kc = 0; kc < 4; ++kc)
    qf[kc] = *reinterpret_cast<const bf16x8*>(&Qp[(size_t)(i0 + lr) * 128 + kc * 32 + lc * 8]);

  f32x4 o[8] = {};            // O^T[d = f*16 + lc*4 + reg][q = qrow]
  float mrun = -1e30f, lrun = 0.f;

  int jlo = i0 - 1023;
  if (jlo < 0) jlo = 0;
  const int j0s = jlo & ~31;
  const int jend = i0 + 15;

  for (int j0 = j0s; j0 <= jend; j0 += 32) {
    // V^T fragments, slot-permuted: slot r -> j0+lc*4+r, slot r+4 -> j0+16+lc*4+r
    uint4 vv[8];
#pragma unroll
    for (int f = 0; f < 8; ++f) {
      const bf16_t* vrow = Vp + (size_t)(f * 16 + lr) * 2048 + j0 + lc * 4;
      uint2 va = *reinterpret_cast<const uint2*>(vrow);
      uint2 vb = *reinterpret_cast<const uint2*>(vrow + 16);
      vv[f].x = va.x; vv[f].y = va.y; vv[f].z = vb.x; vv[f].w = vb.y;
    }

    // S^T = K * Q^T : s0 rows j0..j0+15, s1 rows j0+16..j0+31
    f32x4 s0 = {}, s1 = {};
#pragma unroll
    for (int kc = 0; kc < 4; ++kc) {
      bf16x8 kf0 =
          *reinterpret_cast<const bf16x8*>(&Kp[(size_t)(j0 + lr) * 128 + kc * 32 + lc * 8]);
      bf16x8 kf1 =
          *reinterpret_cast<const bf16x8*>(&Kp[(size_t)(j0 + 16 + lr) * 128 + kc * 32 + lc * 8]);
      s0 = __builtin_amdgcn_mfma_f32_16x16x32_bf16(kf0, qf[kc], s0, 0, 0, 0);
      s1 = __builtin_amdgcn_mfma_f32_16x16x32_bf16(kf1, qf[kc], s1, 0, 0, 0);
    }

    // mask + in-register online softmax (per-lane q; 2 shfls per reduce)
    bool oka[4], okb[4];
    float rm = -1e30f;
#pragma unroll
    for (int r = 0; r < 4; ++r) {
      int ja = j0 + lc * 4 + r;
      int jb = ja + 16;
      oka[r] = (ja <= qrow) && (ja > qrow - 1024);
      okb[r] = (jb <= qrow) && (jb > qrow - 1024);
      float sa = oka[r] ? s0[r] : -1e30f;
      float sb = okb[r] ? s1[r] : -1e30f;
      s0[r] = sa;
      s1[r] = sb;
      rm = fmaxf(rm, fmaxf(sa, sb));
    }
    rm = fmaxf(rm, __shfl_xor(rm, 16));
    rm = fmaxf(rm, __shfl_xor(rm, 32));
    float mnew = fmaxf(mrun, rm);
    float alpha = __expf(mrun - mnew);
    mrun = mnew;

    float p0[4], p1[4], ps = 0.f;
#pragma unroll
    for (int r = 0; r < 4; ++r) {
      p0[r] = oka[r] ? __expf(s0[r] - mnew) : 0.f;  // masked slots contribute exactly 0
      p1[r] = okb[r] ? __expf(s1[r] - mnew) : 0.f;
      ps += p0[r] + p1[r];
    }
    ps += __shfl_xor(ps, 16);
    ps += __shfl_xor(ps, 32);
    lrun = lrun * alpha + ps;

    // P^T fragment (B operand), same slot->j permutation as vv
    bf16_t pb[8];
#pragma unroll
    for (int r = 0; r < 4; ++r) {
      pb[r] = __float2bfloat16(p0[r]);
      pb[r + 4] = __float2bfloat16(p1[r]);
    }
    bf16x8 pfrag = *reinterpret_cast<bf16x8*>(pb);

#pragma unroll
    for (int f = 0; f < 8; ++f) {
#pragma unroll
      for (int r = 0; r < 4; ++r) o[f][r] *= alpha;
      o[f] = __builtin_amdgcn_mfma_f32_16x16x32_bf16(*reinterpret_cast<bf16x8*>(&vv[f]),
                                                     pfrag, o[f], 0, 0, 0);
    }
  }

  // epilogue: O^T[d][q] -> Y[b][q][h*128+d], 8B packed stores
  float inv = 1.f / lrun;
#pragma unroll
  for (int f = 0; f < 8; ++f) {
    bf16_t ob[4];
#pragma unroll
    for (int r = 0; r < 4; ++r) ob[r] = __float2bfloat16(o[f][r] * inv);
    *reinterpret_cast<uint2*>(
        &Y[((size_t)(b * 2048 + qrow)) * 2048 + h * 128 + f * 16 + lc * 4]) =
        *reinterpret_cast<uint2*>(ob);
  }
}

// ---------------- launch ----------------
extern "C" void kernel_launch(void* const* d_in, const int* in_sizes, int n_in,
                              void* d_out, int out_size, void* d_ws, size_t ws_size,
                              hipStream_t stream) {
  const float* x = (const float*)d_in[0];
  const float* cosp = (const float*)d_in[1];
  const float* sinp = (const float*)d_in[2];
  const float* Wa = (const float*)d_in[3];
  const float* Wp = (const float*)d_in[4];
  float* out = (float*)d_out;

  bf16_t* ws = (bf16_t*)d_ws;
  // live ranges allow aliasing: total 62,914,560 bytes of ws
  bf16_t* xb = ws;                  // 8388608  (x bf16)           -> reused as Q
  bf16_t* wab = ws + 8388608;       // 6291456  (W_attn bf16)      -> reused as K,V
  bf16_t* wpb = ws + 14680064;      // 4194304  (W_proj bf16)
  bf16_t* qkv = ws + 18874368;      // 12582912 (qkv bf16)         -> reused as Y,Vt
  bf16_t* Q = xb;                   // 8388608  [B][H][T][HS]
  bf16_t* Kr = wab;                 // 2097152  [B][G][T][HS]
  bf16_t* V = wab + 2097152;        // 2097152  [B][G][T][HS]
  bf16_t* Y = qkv;                  // 8388608  [B][T][H][HS]
  bf16_t* Vt = qkv + 8388608;       // 2097152  [B][G][HS][T]

  cvt_f32_to_bf16<<<4096, 256, 0, stream>>>(x, xb, 1048576);
  cvt_f32_to_bf16<<<3072, 256, 0, stream>>>(Wa, wab, 786432);
  cvt_f32_to_bf16<<<2048, 256, 0, stream>>>(Wp, wpb, 524288);

  // qkv = xb @ wab^T : M=4096 N=3072 K=2048
  gemm_bt<bf16_t><<<dim3(24, 32), 256, 0, stream>>>(xb, wab, qkv, 4096, 3072, 2048);

  rope_scatter<<<4096, 256, 0, stream>>>(qkv, cosp, sinp, Q, Kr, V);

  transpose_v<<<dim3(64, 4, 8), dim3(32, 8), 0, stream>>>(V, Vt);

  attn_swa<<<dim3(32, 16, 2), 256, 0, stream>>>(Q, Kr, Vt, Y);

  // out = Y @ wpb^T : M=4096 N=2048 K=2048 (f32 out)
  gemm_bt<float><<<dim3(16, 32), 256, 0, stream>>>(Y, wpb, out, 4096, 2048, 2048);
}

// Round 4
// 255.785 us; speedup vs baseline: 2.0140x; 2.0140x over previous
//
#include <hip/hip_runtime.h>
#include <hip/hip_bf16.h>
#include <cstdint>
#include <type_traits>

using bf16_t = __hip_bfloat16;
typedef __bf16 bf16x8 __attribute__((ext_vector_type(8)));
typedef float f32x4 __attribute__((ext_vector_type(4)));

typedef __attribute__((address_space(3))) uint32_t lds_u32_t;
typedef const __attribute__((address_space(1))) uint32_t glb_u32_t;

// ---------------- f32 -> bf16 convert, 8 elems/thread ----------------
__global__ void cvt_f32_to_bf16(const float* __restrict__ in, bf16_t* __restrict__ out, int n8) {
  int stride = gridDim.x * blockDim.x;
  for (int i = blockIdx.x * blockDim.x + threadIdx.x; i < n8; i += stride) {
    const float4* p = reinterpret_cast<const float4*>(in) + (size_t)i * 2;
    float4 a = p[0];
    float4 b = p[1];
    bf16_t o[8];
    o[0] = __float2bfloat16(a.x); o[1] = __float2bfloat16(a.y);
    o[2] = __float2bfloat16(a.z); o[3] = __float2bfloat16(a.w);
    o[4] = __float2bfloat16(b.x); o[5] = __float2bfloat16(b.y);
    o[6] = __float2bfloat16(b.z); o[7] = __float2bfloat16(b.w);
    *reinterpret_cast<uint4*>(out + (size_t)i * 8) = *reinterpret_cast<const uint4*>(o);
  }
}

// ---------------- bf16 GEMM: C[M,N] = A[M,K] * Bt[N,K]^T ----------------
// 128x128 tile, BK=32, 4 waves (2x2 of 64x64), mfma_f32_16x16x32_bf16.
// Staging via global_load_lds width=16 (m97 pattern), 2-barrier K-loop.
template <typename OutT>
__global__ __launch_bounds__(256) void gemm_bt(const bf16_t* __restrict__ A,
                                               const bf16_t* __restrict__ Bt,
                                               OutT* __restrict__ C,
                                               int M, int N, int K) {
  __shared__ __align__(16) bf16_t As[128 * 32];
  __shared__ __align__(16) bf16_t Bs[128 * 32];
  const int tid = threadIdx.x;
  const int lane = tid & 63;
  const int w = tid >> 6;
  const int wm = w >> 1, wn = w & 1;
  const int lr = lane & 15, lc = lane >> 4;
  const int m0 = blockIdx.y * 128, n0 = blockIdx.x * 128;

  const int c0 = tid, c1 = tid + 256;
  const bf16_t* a0p = A + (size_t)(m0 + (c0 >> 2)) * K + (c0 & 3) * 8;
  const bf16_t* a1p = A + (size_t)(m0 + (c1 >> 2)) * K + (c1 & 3) * 8;
  const bf16_t* b0p = Bt + (size_t)(n0 + (c0 >> 2)) * K + (c0 & 3) * 8;
  const bf16_t* b1p = Bt + (size_t)(n0 + (c1 >> 2)) * K + (c1 & 3) * 8;

  bf16_t* asb0 = As + w * 512;
  bf16_t* asb1 = As + 2048 + w * 512;
  bf16_t* bsb0 = Bs + w * 512;
  bf16_t* bsb1 = Bs + 2048 + w * 512;

  f32x4 acc[4][4] = {};

  for (int k0 = 0; k0 < K; k0 += 32) {
    __syncthreads();
    __builtin_amdgcn_global_load_lds((glb_u32_t*)(a0p + k0), (lds_u32_t*)asb0, 16, 0, 0);
    __builtin_amdgcn_global_load_lds((glb_u32_t*)(a1p + k0), (lds_u32_t*)asb1, 16, 0, 0);
    __builtin_amdgcn_global_load_lds((glb_u32_t*)(b0p + k0), (lds_u32_t*)bsb0, 16, 0, 0);
    __builtin_amdgcn_global_load_lds((glb_u32_t*)(b1p + k0), (lds_u32_t*)bsb1, 16, 0, 0);
    __syncthreads();

    bf16x8 af[4], bfv[4];
#pragma unroll
    for (int i = 0; i < 4; ++i)
      af[i] = *reinterpret_cast<const bf16x8*>(&As[(wm * 64 + i * 16 + lr) * 32 + lc * 8]);
#pragma unroll
    for (int i = 0; i < 4; ++i)
      bfv[i] = *reinterpret_cast<const bf16x8*>(&Bs[(wn * 64 + i * 16 + lr) * 32 + lc * 8]);
#pragma unroll
    for (int i = 0; i < 4; ++i)
#pragma unroll
      for (int j = 0; j < 4; ++j)
        acc[i][j] = __builtin_amdgcn_mfma_f32_16x16x32_bf16(af[i], bfv[j], acc[i][j], 0, 0, 0);
  }

#pragma unroll
  for (int i = 0; i < 4; ++i)
#pragma unroll
    for (int j = 0; j < 4; ++j) {
      int row = m0 + wm * 64 + i * 16 + lc * 4;
      int col = n0 + wn * 64 + j * 16 + lr;
#pragma unroll
      for (int r = 0; r < 4; ++r) {
        float v = acc[i][j][r];
        if constexpr (std::is_same<OutT, float>::value)
          C[(size_t)(row + r) * N + col] = v;
        else
          C[(size_t)(row + r) * N + col] = __float2bfloat16(v);
      }
    }
}

// ---------------- RoPE + scatter qkv -> Q (scaled), K, V ----------------
__global__ __launch_bounds__(256) void rope_scatter(const bf16_t* __restrict__ qkv,
                                                    const float* __restrict__ cosp,
                                                    const float* __restrict__ sinp,
                                                    bf16_t* __restrict__ Q,
                                                    bf16_t* __restrict__ K,
                                                    bf16_t* __restrict__ V) {
  const int row = blockIdx.x;  // b*2048 + t
  const int b = row >> 11, t = row & 2047;
  const bf16_t* src = qkv + (size_t)row * 3072;
  for (int n = threadIdx.x; n < 3072; n += 256) {
    int g = n / 768;
    int r = n - g * 768;
    int slot = r >> 7;
    int d = r & 127;
    if (slot == 5) {
      V[(((size_t)(b * 4 + g)) * 2048 + t) * 128 + d] = src[n];
    } else {
      float v = __bfloat162float(src[n]);
      float other = __bfloat162float(src[n ^ 64]);
      float c = cosp[t * 128 + d];
      float s = sinp[t * 128 + d];
      float rot = (d < 64) ? -other : other;
      float res = v * c + rot * s;
      if (slot < 4) {
        int h = g * 4 + slot;
        Q[(((size_t)(b * 16 + h)) * 2048 + t) * 128 + d] =
            __float2bfloat16(res * 0.08838834764831843f);
      } else {
        K[(((size_t)(b * 4 + g)) * 2048 + t) * 128 + d] = __float2bfloat16(res);
      }
    }
  }
}

// ---------------- V [bg][t][d] -> Vt [bg][d][t] ----------------
__global__ void transpose_v(const bf16_t* __restrict__ V, bf16_t* __restrict__ Vt) {
  __shared__ bf16_t tile[32][33];
  const int bg = blockIdx.z;
  const int t0 = blockIdx.x * 32;
  const int d0 = blockIdx.y * 32;
  const bf16_t* src = V + (size_t)bg * 2048 * 128;
  bf16_t* dst = Vt + (size_t)bg * 128 * 2048;
#pragma unroll
  for (int i = threadIdx.y; i < 32; i += 8)
    tile[i][threadIdx.x] = src[(size_t)(t0 + i) * 128 + d0 + threadIdx.x];
  __syncthreads();
#pragma unroll
  for (int i = threadIdx.y; i < 32; i += 8)
    dst[(size_t)(d0 + i) * 2048 + t0 + threadIdx.x] = tile[threadIdx.x][i];
}

// ---------------- sliding-window flash attention (cooperative LDS, v4) ----
// Block = 4 waves = 64 consecutive q rows (wave w owns rows i0b+16w..+15).
// Per 32-col j-tile: K staged via global_load_lds with XOR-swizzled SOURCE
// (LDS dest linear; swizzle c^=(row&7)<<4 breaks the 16-way b128 conflict),
// V reg-staged into PV-slot-permuted layout [d][u], u=lc*8+s -> j=4lc+(s&3)+16(s>>2),
// so PV A-frags are single contiguous ds_read_b128. Double-buffered, 2-phase.
// Swapped QK^T (S^T=mfma(K,Q)) in-register softmax as round 3 (verified).
__global__ __launch_bounds__(256) void attn_swa(const bf16_t* __restrict__ Q,
                                                const bf16_t* __restrict__ K,
                                                const bf16_t* __restrict__ Vt,
                                                bf16_t* __restrict__ Y) {
  __shared__ __align__(16) bf16_t Ks[2 * 32 * 128];
  __shared__ __align__(16) bf16_t Vs[2 * 128 * 32];

  const int tid = threadIdx.x;
  const int lane = tid & 63;
  const int w = tid >> 6;
  const int lr = lane & 15, lc = lane >> 4;
  const int b = blockIdx.z, h = blockIdx.y;
  const int g = h >> 2;
  const int i0b = blockIdx.x * 64;       // block's first q row
  const int i0 = i0b + w * 16;           // this wave's q-tile
  const int qrow = i0 + lr;

  const bf16_t* Qp = Q + ((size_t)(b * 16 + h) * 2048) * 128;
  const bf16_t* Kp = K + ((size_t)(b * 4 + g) * 2048) * 128;
  const bf16_t* Vp = Vt + ((size_t)(b * 4 + g) * 128) * 2048;

  // --- staging geometry (per thread) ---
  // K chunk m=tid covers LDS tile row (m>>4), phys col bytes (m&15)*16;
  // logical col = phys ^ ((row&7)<<4)  => pre-swizzled global source.
  const int kmj = tid >> 4;                                  // tile row 0..15
  const int kmc = ((tid & 15) ^ ((tid >> 4) & 7)) * 8;       // src col (elems)
  const bf16_t* Ksrc = Kp + (size_t)kmj * 128 + kmc;         // + (j0+{0,16})*128
  // V chunk: d = tid>>2 (0..63, +64 for chunk1), c = tid&3 covers j' = 8c..8c+7
  const int vd = tid >> 2, vc = tid & 3;
  const bf16_t* Vsrc = Vp + (size_t)vd * 2048 + vc * 8;      // + j0
  const int vdst = vd * 32 + (vc & 1) * 16 + (vc >> 1) * 4;  // elems in Vs tile

  auto stageK = [&](int bufi, int j0) {
    const bf16_t* s = Ksrc + (size_t)j0 * 128;
    __builtin_amdgcn_global_load_lds((glb_u32_t*)s,
                                     (lds_u32_t*)(Ks + bufi * 4096 + w * 512), 16, 0, 0);
    __builtin_amdgcn_global_load_lds((glb_u32_t*)(s + 16 * 128),
                                     (lds_u32_t*)(Ks + bufi * 4096 + 2048 + w * 512), 16, 0, 0);
  };
  auto loadV = [&](int j0, uint4& a, uint4& bqv) {
    a = *reinterpret_cast<const uint4*>(Vsrc + j0);
    bqv = *reinterpret_cast<const uint4*>(Vsrc + 64 * 2048 + j0);
  };
  auto writeV = [&](int bufi, uint4 a, uint4 bqv) {
    bf16_t* p = Vs + bufi * 4096 + vdst;
    *reinterpret_cast<uint2*>(p) = make_uint2(a.x, a.y);
    *reinterpret_cast<uint2*>(p + 8) = make_uint2(a.z, a.w);
    bf16_t* p1 = p + 2048;
    *reinterpret_cast<uint2*>(p1) = make_uint2(bqv.x, bqv.y);
    *reinterpret_cast<uint2*>(p1 + 8) = make_uint2(bqv.z, bqv.w);
  };

  // Q fragments (once)
  bf16x8 qf[4];
#pragma unroll
  for (int kc = 0; kc < 4; ++kc)
    qf[kc] = *reinterpret_cast<const bf16x8*>(&Qp[(size_t)(i0 + lr) * 128 + kc * 32 + lc * 8]);

  f32x4 o[8] = {};
  float mrun = -1e30f, lrun = 0.f;

  int lo = i0b - 1023;
  if (lo < 0) lo = 0;
  const int jstart = lo & ~31;
  const int jlast = i0b + 32;  // last tile start (covers i0b+32..+63)
  const int kxor = (lr & 7) << 4;

  // prologue: stage tile jstart into buf 0
  {
    stageK(0, jstart);
    uint4 va, vb;
    loadV(jstart, va, vb);
    writeV(0, va, vb);
  }
  __syncthreads();

  int buf = 0;
  for (int j0 = jstart; j0 <= jlast; j0 += 32) {
    const int nxt = j0 + 32;
    uint4 va, vb;
    const bool do_stage = (nxt <= jlast);
    if (do_stage) {
      stageK(buf ^ 1, nxt);
      loadV(nxt, va, vb);
    }

    const bool active = (j0 <= i0 + 15) && (j0 + 31 > i0 - 1024);
    if (active) {
      const bf16_t* Kb = Ks + buf * 4096;
      const bf16_t* Vb = Vs + buf * 4096;
      // S^T = K * Q^T
      f32x4 s0 = {}, s1 = {};
#pragma unroll
      for (int kc = 0; kc < 4; ++kc) {
        int col = ((kc * 64 + lc * 16) ^ kxor) >> 1;  // element offset in row
        bf16x8 kf0 = *reinterpret_cast<const bf16x8*>(Kb + lr * 128 + col);
        bf16x8 kf1 = *reinterpret_cast<const bf16x8*>(Kb + (16 + lr) * 128 + col);
        s0 = __builtin_amdgcn_mfma_f32_16x16x32_bf16(kf0, qf[kc], s0, 0, 0, 0);
        s1 = __builtin_amdgcn_mfma_f32_16x16x32_bf16(kf1, qf[kc], s1, 0, 0, 0);
      }
      // V fragments (consumed after softmax; latency hides under it)
      bf16x8 vvf[8];
#pragma unroll
      for (int f = 0; f < 8; ++f)
        vvf[f] = *reinterpret_cast<const bf16x8*>(Vb + (f * 16 + lr) * 32 + lc * 8);

      // mask + in-register online softmax
      bool oka[4], okb[4];
      float rm = -1e30f;
#pragma unroll
      for (int r = 0; r < 4; ++r) {
        int ja = j0 + lc * 4 + r;
        int jb = ja + 16;
        oka[r] = (ja <= qrow) && (ja > qrow - 1024);
        okb[r] = (jb <= qrow) && (jb > qrow - 1024);
        float sa = oka[r] ? s0[r] : -1e30f;
        float sb = okb[r] ? s1[r] : -1e30f;
        s0[r] = sa;
        s1[r] = sb;
        rm = fmaxf(rm, fmaxf(sa, sb));
      }
      rm = fmaxf(rm, __shfl_xor(rm, 16));
      rm = fmaxf(rm, __shfl_xor(rm, 32));
      float mnew = fmaxf(mrun, rm);
      float alpha = __expf(mrun - mnew);
      mrun = mnew;

      float p0[4], p1[4], ps = 0.f;
#pragma unroll
      for (int r = 0; r < 4; ++r) {
        p0[r] = oka[r] ? __expf(s0[r] - mnew) : 0.f;
        p1[r] = okb[r] ? __expf(s1[r] - mnew) : 0.f;
        ps += p0[r] + p1[r];
      }
      ps += __shfl_xor(ps, 16);
      ps += __shfl_xor(ps, 32);
      lrun = lrun * alpha + ps;

      bf16_t pb[8];
#pragma unroll
      for (int r = 0; r < 4; ++r) {
        pb[r] = __float2bfloat16(p0[r]);
        pb[r + 4] = __float2bfloat16(p1[r]);
      }
      bf16x8 pfrag = *reinterpret_cast<bf16x8*>(pb);

#pragma unroll
      for (int f = 0; f < 8; ++f) {
#pragma unroll
        for (int r = 0; r < 4; ++r) o[f][r] *= alpha;
        o[f] = __builtin_amdgcn_mfma_f32_16x16x32_bf16(vvf[f], pfrag, o[f], 0, 0, 0);
      }
    }

    if (do_stage) writeV(buf ^ 1, va, vb);
    __syncthreads();  // drains vmcnt (K gload_lds) + lgkm (V writes)
    buf ^= 1;
  }

  // epilogue: O^T[d][q] -> Y[b][q][h*128+d], 8B packed stores
  float inv = 1.f / lrun;
#pragma unroll
  for (int f = 0; f < 8; ++f) {
    bf16_t ob[4];
#pragma unroll
    for (int r = 0; r < 4; ++r) ob[r] = __float2bfloat16(o[f][r] * inv);
    *reinterpret_cast<uint2*>(
        &Y[((size_t)(b * 2048 + qrow)) * 2048 + h * 128 + f * 16 + lc * 4]) =
        *reinterpret_cast<uint2*>(ob);
  }
}

// ---------------- launch ----------------
extern "C" void kernel_launch(void* const* d_in, const int* in_sizes, int n_in,
                              void* d_out, int out_size, void* d_ws, size_t ws_size,
                              hipStream_t stream) {
  const float* x = (const float*)d_in[0];
  const float* cosp = (const float*)d_in[1];
  const float* sinp = (const float*)d_in[2];
  const float* Wa = (const float*)d_in[3];
  const float* Wp = (const float*)d_in[4];
  float* out = (float*)d_out;

  bf16_t* ws = (bf16_t*)d_ws;
  bf16_t* xb = ws;                  // 8388608  (x bf16)           -> reused as Q
  bf16_t* wab = ws + 8388608;       // 6291456  (W_attn bf16)      -> reused as K,V
  bf16_t* wpb = ws + 14680064;      // 4194304  (W_proj bf16)
  bf16_t* qkv = ws + 18874368;      // 12582912 (qkv bf16)         -> reused as Y,Vt
  bf16_t* Q = xb;                   // [B][H][T][HS]
  bf16_t* Kr = wab;                 // [B][G][T][HS]
  bf16_t* V = wab + 2097152;        // [B][G][T][HS]
  bf16_t* Y = qkv;                  // [B][T][H][HS]
  bf16_t* Vt = qkv + 8388608;       // [B][G][HS][T]

  cvt_f32_to_bf16<<<4096, 256, 0, stream>>>(x, xb, 1048576);
  cvt_f32_to_bf16<<<3072, 256, 0, stream>>>(Wa, wab, 786432);
  cvt_f32_to_bf16<<<2048, 256, 0, stream>>>(Wp, wpb, 524288);

  gemm_bt<bf16_t><<<dim3(24, 32), 256, 0, stream>>>(xb, wab, qkv, 4096, 3072, 2048);

  rope_scatter<<<4096, 256, 0, stream>>>(qkv, cosp, sinp, Q, Kr, V);

  transpose_v<<<dim3(64, 4, 8), dim3(32, 8), 0, stream>>>(V, Vt);

  attn_swa<<<dim3(32, 16, 2), 256, 0, stream>>>(Q, Kr, Vt, Y);

  gemm_bt<float><<<dim3(16, 32), 256, 0, stream>>>(Y, wpb, out, 4096, 2048, 2048);
}

// Round 5
// 254.283 us; speedup vs baseline: 2.0259x; 1.0059x over previous
//
#include <hip/hip_runtime.h>
#include <hip/hip_bf16.h>
#include <cstdint>
#include <type_traits>

using bf16_t = __hip_bfloat16;
typedef __bf16 bf16x8 __attribute__((ext_vector_type(8)));
typedef float f32x4 __attribute__((ext_vector_type(4)));

typedef __attribute__((address_space(3))) uint32_t lds_u32_t;
typedef const __attribute__((address_space(1))) uint32_t glb_u32_t;

// ---------------- f32 -> bf16 convert, 8 elems/thread ----------------
__global__ void cvt_f32_to_bf16(const float* __restrict__ in, bf16_t* __restrict__ out, int n8) {
  int stride = gridDim.x * blockDim.x;
  for (int i = blockIdx.x * blockDim.x + threadIdx.x; i < n8; i += stride) {
    const float4* p = reinterpret_cast<const float4*>(in) + (size_t)i * 2;
    float4 a = p[0];
    float4 b = p[1];
    bf16_t o[8];
    o[0] = __float2bfloat16(a.x); o[1] = __float2bfloat16(a.y);
    o[2] = __float2bfloat16(a.z); o[3] = __float2bfloat16(a.w);
    o[4] = __float2bfloat16(b.x); o[5] = __float2bfloat16(b.y);
    o[6] = __float2bfloat16(b.z); o[7] = __float2bfloat16(b.w);
    *reinterpret_cast<uint4*>(out + (size_t)i * 8) = *reinterpret_cast<const uint4*>(o);
  }
}

// ---------------- bf16 GEMM: C[M,N] = A[M,K] * Bt[N,K]^T ----------------
// 128x128 tile, BK=32, 4 waves (2x2 of 64x64), mfma_f32_16x16x32_bf16.
// Staging via global_load_lds width=16 (m97 pattern), 2-barrier K-loop.
template <typename OutT>
__global__ __launch_bounds__(256) void gemm_bt(const bf16_t* __restrict__ A,
                                               const bf16_t* __restrict__ Bt,
                                               OutT* __restrict__ C,
                                               int M, int N, int K) {
  __shared__ __align__(16) bf16_t As[128 * 32];
  __shared__ __align__(16) bf16_t Bs[128 * 32];
  const int tid = threadIdx.x;
  const int lane = tid & 63;
  const int w = tid >> 6;
  const int wm = w >> 1, wn = w & 1;
  const int lr = lane & 15, lc = lane >> 4;
  const int m0 = blockIdx.y * 128, n0 = blockIdx.x * 128;

  const int c0 = tid, c1 = tid + 256;
  const bf16_t* a0p = A + (size_t)(m0 + (c0 >> 2)) * K + (c0 & 3) * 8;
  const bf16_t* a1p = A + (size_t)(m0 + (c1 >> 2)) * K + (c1 & 3) * 8;
  const bf16_t* b0p = Bt + (size_t)(n0 + (c0 >> 2)) * K + (c0 & 3) * 8;
  const bf16_t* b1p = Bt + (size_t)(n0 + (c1 >> 2)) * K + (c1 & 3) * 8;

  bf16_t* asb0 = As + w * 512;
  bf16_t* asb1 = As + 2048 + w * 512;
  bf16_t* bsb0 = Bs + w * 512;
  bf16_t* bsb1 = Bs + 2048 + w * 512;

  f32x4 acc[4][4] = {};

  for (int k0 = 0; k0 < K; k0 += 32) {
    __syncthreads();
    __builtin_amdgcn_global_load_lds((glb_u32_t*)(a0p + k0), (lds_u32_t*)asb0, 16, 0, 0);
    __builtin_amdgcn_global_load_lds((glb_u32_t*)(a1p + k0), (lds_u32_t*)asb1, 16, 0, 0);
    __builtin_amdgcn_global_load_lds((glb_u32_t*)(b0p + k0), (lds_u32_t*)bsb0, 16, 0, 0);
    __builtin_amdgcn_global_load_lds((glb_u32_t*)(b1p + k0), (lds_u32_t*)bsb1, 16, 0, 0);
    __syncthreads();

    bf16x8 af[4], bfv[4];
#pragma unroll
    for (int i = 0; i < 4; ++i)
      af[i] = *reinterpret_cast<const bf16x8*>(&As[(wm * 64 + i * 16 + lr) * 32 + lc * 8]);
#pragma unroll
    for (int i = 0; i < 4; ++i)
      bfv[i] = *reinterpret_cast<const bf16x8*>(&Bs[(wn * 64 + i * 16 + lr) * 32 + lc * 8]);
#pragma unroll
    for (int i = 0; i < 4; ++i)
#pragma unroll
      for (int j = 0; j < 4; ++j)
        acc[i][j] = __builtin_amdgcn_mfma_f32_16x16x32_bf16(af[i], bfv[j], acc[i][j], 0, 0, 0);
  }

#pragma unroll
  for (int i = 0; i < 4; ++i)
#pragma unroll
    for (int j = 0; j < 4; ++j) {
      int row = m0 + wm * 64 + i * 16 + lc * 4;
      int col = n0 + wn * 64 + j * 16 + lr;
#pragma unroll
      for (int r = 0; r < 4; ++r) {
        float v = acc[i][j][r];
        if constexpr (std::is_same<OutT, float>::value)
          C[(size_t)(row + r) * N + col] = v;
        else
          C[(size_t)(row + r) * N + col] = __float2bfloat16(v);
      }
    }
}

// ---------------- RoPE + scatter qkv -> Q (scaled), K, V ----------------
__global__ __launch_bounds__(256) void rope_scatter(const bf16_t* __restrict__ qkv,
                                                    const float* __restrict__ cosp,
                                                    const float* __restrict__ sinp,
                                                    bf16_t* __restrict__ Q,
                                                    bf16_t* __restrict__ K,
                                                    bf16_t* __restrict__ V) {
  const int row = blockIdx.x;  // b*2048 + t
  const int b = row >> 11, t = row & 2047;
  const bf16_t* src = qkv + (size_t)row * 3072;
  for (int n = threadIdx.x; n < 3072; n += 256) {
    int g = n / 768;
    int r = n - g * 768;
    int slot = r >> 7;
    int d = r & 127;
    if (slot == 5) {
      V[(((size_t)(b * 4 + g)) * 2048 + t) * 128 + d] = src[n];
    } else {
      float v = __bfloat162float(src[n]);
      float other = __bfloat162float(src[n ^ 64]);
      float c = cosp[t * 128 + d];
      float s = sinp[t * 128 + d];
      float rot = (d < 64) ? -other : other;
      float res = v * c + rot * s;
      if (slot < 4) {
        int h = g * 4 + slot;
        Q[(((size_t)(b * 16 + h)) * 2048 + t) * 128 + d] =
            __float2bfloat16(res * 0.08838834764831843f);
      } else {
        K[(((size_t)(b * 4 + g)) * 2048 + t) * 128 + d] = __float2bfloat16(res);
      }
    }
  }
}

// ---------------- V [bg][t][d] -> Vt [bg][d][t] ----------------
__global__ void transpose_v(const bf16_t* __restrict__ V, bf16_t* __restrict__ Vt) {
  __shared__ bf16_t tile[32][33];
  const int bg = blockIdx.z;
  const int t0 = blockIdx.x * 32;
  const int d0 = blockIdx.y * 32;
  const bf16_t* src = V + (size_t)bg * 2048 * 128;
  bf16_t* dst = Vt + (size_t)bg * 128 * 2048;
#pragma unroll
  for (int i = threadIdx.y; i < 32; i += 8)
    tile[i][threadIdx.x] = src[(size_t)(t0 + i) * 128 + d0 + threadIdx.x];
  __syncthreads();
#pragma unroll
  for (int i = threadIdx.y; i < 32; i += 8)
    dst[(size_t)(d0 + i) * 2048 + t0 + threadIdx.x] = tile[threadIdx.x][i];
}

// ---------------- sliding-window flash attention (v5) --------------------
// Round-4 cooperative-LDS structure + three fixes:
//  (a) Vs rows padded 32->40 elems (80B, 5x16B, coprime stride) -> V-read
//      ds_read_b128 hits all 8 bank-octets uniformly (was 8-way conflict).
//  (b) defer-max rescale (T13, THR=8): skip alpha path unless tile max grew.
//  (c) wave-uniform interior-tile fast path: skip masking when whole tile
//      is inside every lane's window.
#define VROW 40
__global__ __launch_bounds__(256) void attn_swa(const bf16_t* __restrict__ Q,
                                                const bf16_t* __restrict__ K,
                                                const bf16_t* __restrict__ Vt,
                                                bf16_t* __restrict__ Y) {
  __shared__ __align__(16) bf16_t Ks[2 * 32 * 128];
  __shared__ __align__(16) bf16_t Vs[2 * 128 * VROW];

  const int tid = threadIdx.x;
  const int lane = tid & 63;
  const int w = tid >> 6;
  const int lr = lane & 15, lc = lane >> 4;
  const int b = blockIdx.z, h = blockIdx.y;
  const int g = h >> 2;
  const int i0b = blockIdx.x * 64;       // block's first q row
  const int i0 = i0b + w * 16;           // this wave's q-tile
  const int qrow = i0 + lr;

  const bf16_t* Qp = Q + ((size_t)(b * 16 + h) * 2048) * 128;
  const bf16_t* Kp = K + ((size_t)(b * 4 + g) * 2048) * 128;
  const bf16_t* Vp = Vt + ((size_t)(b * 4 + g) * 128) * 2048;

  // K chunk: row (tid>>4), src col XOR-preswizzled (dest linear)
  const int kmj = tid >> 4;
  const int kmc = ((tid & 15) ^ ((tid >> 4) & 7)) * 8;
  const bf16_t* Ksrc = Kp + (size_t)kmj * 128 + kmc;
  // V chunk: d = tid>>2 (+64 for chunk1), vc = tid&3
  const int vd = tid >> 2, vc = tid & 3;
  const bf16_t* Vsrc = Vp + (size_t)vd * 2048 + vc * 8;
  const int vdst = vd * VROW + (vc & 1) * 16 + (vc >> 1) * 4;

  auto stageK = [&](int bufi, int j0) {
    const bf16_t* s = Ksrc + (size_t)j0 * 128;
    __builtin_amdgcn_global_load_lds((glb_u32_t*)s,
                                     (lds_u32_t*)(Ks + bufi * 4096 + w * 512), 16, 0, 0);
    __builtin_amdgcn_global_load_lds((glb_u32_t*)(s + 16 * 128),
                                     (lds_u32_t*)(Ks + bufi * 4096 + 2048 + w * 512), 16, 0, 0);
  };
  auto loadV = [&](int j0, uint4& a, uint4& bqv) {
    a = *reinterpret_cast<const uint4*>(Vsrc + j0);
    bqv = *reinterpret_cast<const uint4*>(Vsrc + 64 * 2048 + j0);
  };
  auto writeV = [&](int bufi, uint4 a, uint4 bqv) {
    bf16_t* p = Vs + bufi * 128 * VROW + vdst;
    *reinterpret_cast<uint2*>(p) = make_uint2(a.x, a.y);
    *reinterpret_cast<uint2*>(p + 8) = make_uint2(a.z, a.w);
    bf16_t* p1 = p + 64 * VROW;
    *reinterpret_cast<uint2*>(p1) = make_uint2(bqv.x, bqv.y);
    *reinterpret_cast<uint2*>(p1 + 8) = make_uint2(bqv.z, bqv.w);
  };

  bf16x8 qf[4];
#pragma unroll
  for (int kc = 0; kc < 4; ++kc)
    qf[kc] = *reinterpret_cast<const bf16x8*>(&Qp[(size_t)(i0 + lr) * 128 + kc * 32 + lc * 8]);

  f32x4 o[8] = {};
  float mrun = -1e30f, lrun = 0.f;

  int lo = i0b - 1023;
  if (lo < 0) lo = 0;
  const int jstart = lo & ~31;
  const int jlast = i0b + 32;
  const int kxor = (lr & 7) << 4;

  {
    stageK(0, jstart);
    uint4 va, vb;
    loadV(jstart, va, vb);
    writeV(0, va, vb);
  }
  __syncthreads();

  int buf = 0;
  for (int j0 = jstart; j0 <= jlast; j0 += 32) {
    const int nxt = j0 + 32;
    uint4 va, vb;
    const bool do_stage = (nxt <= jlast);
    if (do_stage) {
      stageK(buf ^ 1, nxt);
      loadV(nxt, va, vb);
    }

    const bool active = (j0 <= i0 + 15) && (j0 + 31 > i0 - 1024);
    if (active) {
      const bf16_t* Kb = Ks + buf * 4096;
      const bf16_t* Vb = Vs + buf * 128 * VROW;
      // S^T = K * Q^T
      f32x4 s0 = {}, s1 = {};
#pragma unroll
      for (int kc = 0; kc < 4; ++kc) {
        int col = ((kc * 64 + lc * 16) ^ kxor) >> 1;
        bf16x8 kf0 = *reinterpret_cast<const bf16x8*>(Kb + lr * 128 + col);
        bf16x8 kf1 = *reinterpret_cast<const bf16x8*>(Kb + (16 + lr) * 128 + col);
        s0 = __builtin_amdgcn_mfma_f32_16x16x32_bf16(kf0, qf[kc], s0, 0, 0, 0);
        s1 = __builtin_amdgcn_mfma_f32_16x16x32_bf16(kf1, qf[kc], s1, 0, 0, 0);
      }
      bf16x8 vvf[8];
#pragma unroll
      for (int f = 0; f < 8; ++f)
        vvf[f] = *reinterpret_cast<const bf16x8*>(Vb + (f * 16 + lr) * VROW + lc * 8);

      // ---- masking (skipped on wave-uniform interior tiles) ----
      const bool full = (j0 + 31 <= i0) && (j0 >= i0 - 1008);
      float rm;
      if (full) {
        rm = fmaxf(fmaxf(fmaxf(s0[0], s0[1]), fmaxf(s0[2], s0[3])),
                   fmaxf(fmaxf(s1[0], s1[1]), fmaxf(s1[2], s1[3])));
      } else {
        rm = -1e30f;
#pragma unroll
        for (int r = 0; r < 4; ++r) {
          int ja = j0 + lc * 4 + r;
          int jb = ja + 16;
          bool oka = (ja <= qrow) && (ja > qrow - 1024);
          bool okb = (jb <= qrow) && (jb > qrow - 1024);
          float sa = oka ? s0[r] : -1e30f;
          float sb = okb ? s1[r] : -1e30f;
          s0[r] = sa;
          s1[r] = sb;
          rm = fmaxf(rm, fmaxf(sa, sb));
        }
      }
      rm = fmaxf(rm, __shfl_xor(rm, 16));
      rm = fmaxf(rm, __shfl_xor(rm, 32));

      // ---- defer-max (T13, THR=8): rescale only when max grew past slack ----
      if (!__all(rm <= mrun + 8.0f)) {
        float mnew = fmaxf(mrun, rm);
        float alpha = __expf(mrun - mnew);
        mrun = mnew;
        lrun *= alpha;
#pragma unroll
        for (int f = 0; f < 8; ++f)
#pragma unroll
          for (int r = 0; r < 4; ++r) o[f][r] *= alpha;
      }

      // ---- P = exp(S - mrun); masked slots are exactly 0 (s = -1e30) ----
      float p0[4], p1[4], ps = 0.f;
#pragma unroll
      for (int r = 0; r < 4; ++r) {
        p0[r] = __expf(s0[r] - mrun);
        p1[r] = __expf(s1[r] - mrun);
        ps += p0[r] + p1[r];
      }
      ps += __shfl_xor(ps, 16);
      ps += __shfl_xor(ps, 32);
      lrun += ps;

      bf16_t pb[8];
#pragma unroll
      for (int r = 0; r < 4; ++r) {
        pb[r] = __float2bfloat16(p0[r]);
        pb[r + 4] = __float2bfloat16(p1[r]);
      }
      bf16x8 pfrag = *reinterpret_cast<bf16x8*>(pb);

#pragma unroll
      for (int f = 0; f < 8; ++f)
        o[f] = __builtin_amdgcn_mfma_f32_16x16x32_bf16(vvf[f], pfrag, o[f], 0, 0, 0);
    }

    if (do_stage) writeV(buf ^ 1, va, vb);
    __syncthreads();
    buf ^= 1;
  }

  float inv = 1.f / lrun;
#pragma unroll
  for (int f = 0; f < 8; ++f) {
    bf16_t ob[4];
#pragma unroll
    for (int r = 0; r < 4; ++r) ob[r] = __float2bfloat16(o[f][r] * inv);
    *reinterpret_cast<uint2*>(
        &Y[((size_t)(b * 2048 + qrow)) * 2048 + h * 128 + f * 16 + lc * 4]) =
        *reinterpret_cast<uint2*>(ob);
  }
}

// ---------------- launch ----------------
extern "C" void kernel_launch(void* const* d_in, const int* in_sizes, int n_in,
                              void* d_out, int out_size, void* d_ws, size_t ws_size,
                              hipStream_t stream) {
  const float* x = (const float*)d_in[0];
  const float* cosp = (const float*)d_in[1];
  const float* sinp = (const float*)d_in[2];
  const float* Wa = (const float*)d_in[3];
  const float* Wp = (const float*)d_in[4];
  float* out = (float*)d_out;

  bf16_t* ws = (bf16_t*)d_ws;
  bf16_t* xb = ws;                  // x bf16 -> reused as Q
  bf16_t* wab = ws + 8388608;       // W_attn bf16 -> reused as K,V
  bf16_t* wpb = ws + 14680064;      // W_proj bf16
  bf16_t* qkv = ws + 18874368;      // qkv bf16 -> reused as Y,Vt
  bf16_t* Q = xb;                   // [B][H][T][HS]
  bf16_t* Kr = wab;                 // [B][G][T][HS]
  bf16_t* V = wab + 2097152;        // [B][G][T][HS]
  bf16_t* Y = qkv;                  // [B][T][H][HS]
  bf16_t* Vt = qkv + 8388608;       // [B][G][HS][T]

  cvt_f32_to_bf16<<<4096, 256, 0, stream>>>(x, xb, 1048576);
  cvt_f32_to_bf16<<<3072, 256, 0, stream>>>(Wa, wab, 786432);
  cvt_f32_to_bf16<<<2048, 256, 0, stream>>>(Wp, wpb, 524288);

  gemm_bt<bf16_t><<<dim3(24, 32), 256, 0, stream>>>(xb, wab, qkv, 4096, 3072, 2048);

  rope_scatter<<<4096, 256, 0, stream>>>(qkv, cosp, sinp, Q, Kr, V);

  transpose_v<<<dim3(64, 4, 8), dim3(32, 8), 0, stream>>>(V, Vt);

  attn_swa<<<dim3(32, 16, 2), 256, 0, stream>>>(Q, Kr, Vt, Y);

  gemm_bt<float><<<dim3(16, 32), 256, 0, stream>>>(Y, wpb, out, 4096, 2048, 2048);
}